// Round 1
// baseline (133.768 us; speedup 1.0000x reference)
//
#include <hip/hip_runtime.h>

#define H 1024
#define B2 2
#define LEN 8192
#define V 50000

__device__ __forceinline__ float dot4(float4 a, float4 b) {
    return a.x * b.x + a.y * b.y + a.z * b.z + a.w * b.w;
}

// ---------------------------------------------------------------------------
// K1: u partials.  u[h] = sum_k v[k] * attn_w[k*2048 + 1024 + h]
// grid (4 h-chunks, 16 k-chunks) x 256 threads
// ---------------------------------------------------------------------------
__global__ void k_upart(const float* __restrict__ attn_w,
                        const float* __restrict__ v,
                        float* __restrict__ upart) {
    int h  = blockIdx.x * 256 + threadIdx.x;   // 0..1023
    int kc = blockIdx.y;                       // 0..15
    float acc = 0.f;
#pragma unroll 8
    for (int i = 0; i < 64; ++i) {
        int k = kc * 64 + i;
        acc += v[k] * attn_w[(long)k * (2 * H) + H + h];
    }
    upart[kc * H + h] = acc;
}

// ---------------------------------------------------------------------------
// K2: reduce u partials; also gather the embedding output rows.
// grid 4 x 256
// ---------------------------------------------------------------------------
__global__ void k_ured_emb(const float* __restrict__ upart,
                           float* __restrict__ u,
                           const int* __restrict__ ids,
                           const float* __restrict__ emb,
                           float* __restrict__ out_emb) {
    int h = blockIdx.x * 256 + threadIdx.x;    // 0..1023
    float acc = 0.f;
#pragma unroll
    for (int kc = 0; kc < 16; ++kc) acc += upart[kc * H + h];
    u[h] = acc;
    out_emb[h]     = emb[(long)ids[0] * H + h];
    out_emb[H + h] = emb[(long)ids[1] * H + h];
}

// ---------------------------------------------------------------------------
// K3: GRU cell. One block (256 thr) per output element hh.
// Computes gx[b][g*H+hh], gh[b][g*H+hh] for 3 gates x 2 batches, then gates.
// ---------------------------------------------------------------------------
__global__ void k_gru(const int* __restrict__ ids,
                      const float* __restrict__ emb,
                      const float* __restrict__ lctx,
                      const float* __restrict__ lhid,
                      const float* __restrict__ w_ih,
                      const float* __restrict__ w_hh,
                      const float* __restrict__ b_ih,
                      const float* __restrict__ b_hh,
                      float* __restrict__ o_hidden,
                      float* __restrict__ o_rnn) {
    int hh = blockIdx.x;          // 0..1023
    int t  = threadIdx.x;         // 0..255
    int kb = t * 8;               // x index base (0..2040)

    // x[b] = [emb_row_b (1024) | last_context_b (1024)]
    float4 x0a, x0b, x1a, x1b;
    if (kb < H) {
        const float* p0 = emb + (long)ids[0] * H + kb;
        const float* p1 = emb + (long)ids[1] * H + kb;
        x0a = *(const float4*)p0;       x0b = *(const float4*)(p0 + 4);
        x1a = *(const float4*)p1;       x1b = *(const float4*)(p1 + 4);
    } else {
        const float* p0 = lctx + (kb - H);
        const float* p1 = lctx + H + (kb - H);
        x0a = *(const float4*)p0;       x0b = *(const float4*)(p0 + 4);
        x1a = *(const float4*)p1;       x1b = *(const float4*)(p1 + 4);
    }
    int kb2 = t * 4;              // h index base (0..1020)
    float4 h0 = *(const float4*)(lhid + kb2);
    float4 h1 = *(const float4*)(lhid + H + kb2);

    __shared__ float lds[3][4][4];
    for (int g = 0; g < 3; ++g) {
        const float* wi = w_ih + ((long)g * H + hh) * (2 * H) + kb;
        const float* wh = w_hh + ((long)g * H + hh) * H + kb2;
        float4 wa = *(const float4*)wi;
        float4 wb = *(const float4*)(wi + 4);
        float4 wc = *(const float4*)wh;
        float a0 = dot4(wa, x0a) + dot4(wb, x0b);
        float a1 = dot4(wa, x1a) + dot4(wb, x1b);
        float c0 = dot4(wc, h0);
        float c1 = dot4(wc, h1);
        for (int off = 32; off; off >>= 1) {
            a0 += __shfl_down(a0, off, 64);
            a1 += __shfl_down(a1, off, 64);
            c0 += __shfl_down(c0, off, 64);
            c1 += __shfl_down(c1, off, 64);
        }
        if ((t & 63) == 0) {
            int w = t >> 6;
            lds[g][w][0] = a0; lds[g][w][1] = a1;
            lds[g][w][2] = c0; lds[g][w][3] = c1;
        }
    }
    __syncthreads();
    if (t == 0) {
        float gx[3][2], gh[3][2];
        for (int g = 0; g < 3; ++g) {
            float s0 = 0, s1 = 0, s2 = 0, s3 = 0;
            for (int w = 0; w < 4; ++w) {
                s0 += lds[g][w][0]; s1 += lds[g][w][1];
                s2 += lds[g][w][2]; s3 += lds[g][w][3];
            }
            float bi = b_ih[g * H + hh], bh = b_hh[g * H + hh];
            gx[g][0] = s0 + bi; gx[g][1] = s1 + bi;
            gh[g][0] = s2 + bh; gh[g][1] = s3 + bh;
        }
        for (int b = 0; b < B2; ++b) {
            float r  = 1.f / (1.f + expf(-(gx[0][b] + gh[0][b])));
            float z  = 1.f / (1.f + expf(-(gx[1][b] + gh[1][b])));
            float n  = tanhf(gx[2][b] + r * gh[2][b]);
            float hp = lhid[b * H + hh];
            float hn = (1.f - z) * n + z * hp;
            o_hidden[b * H + hh] = hn;
            o_rnn[b * H + hh]    = hn;
        }
    }
}

// ---------------------------------------------------------------------------
// K4: energies[row] = enc[row,:] . u     (row = b*L + l, wave per row)
// grid 4096 x 256 (4 waves/block = 4 rows/block)
// ---------------------------------------------------------------------------
__global__ void k_energy(const float* __restrict__ enc,
                         const float* __restrict__ u,
                         float* __restrict__ en) {
    int row  = (blockIdx.x << 2) + (threadIdx.x >> 6);
    int lane = threadIdx.x & 63;
    const float* e = enc + (long)row * H;
    float acc = 0.f;
#pragma unroll
    for (int c = 0; c < 4; ++c) {
        int k = c * 256 + lane * 4;
        float4 ev = *(const float4*)(e + k);
        float4 uv = *(const float4*)(u + k);
        acc += dot4(ev, uv);
    }
    for (int off = 32; off; off >>= 1) acc += __shfl_down(acc, off, 64);
    if (lane == 0) en[row] = acc;
}

// ---------------------------------------------------------------------------
// K5: softmax over L=8192, in place (en -> normalized weights). block per b.
// ---------------------------------------------------------------------------
__global__ void k_softmax(float* __restrict__ en) {
    int b = blockIdx.x;
    float* e = en + b * LEN;
    int t = threadIdx.x;                 // 0..1023
    __shared__ float lds[16];
    float vals[8];
    float m = -3.4e38f;
#pragma unroll
    for (int i = 0; i < 8; ++i) { vals[i] = e[i * 1024 + t]; m = fmaxf(m, vals[i]); }
    for (int off = 32; off; off >>= 1) m = fmaxf(m, __shfl_xor(m, off, 64));
    if ((t & 63) == 0) lds[t >> 6] = m;
    __syncthreads();
    m = lds[0];
#pragma unroll
    for (int w = 1; w < 16; ++w) m = fmaxf(m, lds[w]);
    __syncthreads();
    float s = 0.f;
#pragma unroll
    for (int i = 0; i < 8; ++i) { vals[i] = expf(vals[i] - m); s += vals[i]; }
    for (int off = 32; off; off >>= 1) s += __shfl_xor(s, off, 64);
    if ((t & 63) == 0) lds[t >> 6] = s;
    __syncthreads();
    float tot = 0.f;
#pragma unroll
    for (int w = 0; w < 16; ++w) tot += lds[w];
    float inv = 1.f / tot;
#pragma unroll
    for (int i = 0; i < 8; ++i) e[i * 1024 + t] = vals[i] * inv;
}

// ---------------------------------------------------------------------------
// K6: context partials. block = (b, l-chunk of 64); thread owns 4 h's.
// grid 256 x 256
// ---------------------------------------------------------------------------
__global__ void k_ctx_part(const float* __restrict__ enc,
                           const float* __restrict__ p,
                           float* __restrict__ part) {
    int b  = blockIdx.x >> 7;      // 0..1
    int lc = blockIdx.x & 127;     // 0..127
    int t  = threadIdx.x;
    const float* e  = enc + ((long)b * LEN + lc * 64) * H + t * 4;
    const float* pw = p + b * LEN + lc * 64;
    float4 acc = {0.f, 0.f, 0.f, 0.f};
#pragma unroll 4
    for (int i = 0; i < 64; ++i) {
        float w = pw[i];
        float4 ev = *(const float4*)(e + (long)i * H);
        acc.x += w * ev.x; acc.y += w * ev.y; acc.z += w * ev.z; acc.w += w * ev.w;
    }
    *(float4*)(part + (long)blockIdx.x * H + t * 4) = acc;
}

// K7: reduce context partials -> context output. grid 8 x 256.
__global__ void k_ctx_red(const float* __restrict__ part,
                          float* __restrict__ out_ctx) {
    int idx = blockIdx.x * 256 + threadIdx.x;  // 0..2047 = b*H+h
    int b = idx >> 10, h = idx & 1023;
    float acc = 0.f;
#pragma unroll 8
    for (int lc = 0; lc < 128; ++lc) acc += part[((b << 7) + lc) * H + h];
    out_ctx[idx] = acc;
}

// ---------------------------------------------------------------------------
// K8: output projection. out[b,o] = cat[b,:] . out_w[o,:] + out_b[o]
// block of 256 handles 8 rows; per-thread cat slice (8 k's) in registers.
// grid 6250 x 256
// ---------------------------------------------------------------------------
__global__ void k_out(const float* __restrict__ ow,
                      const float* __restrict__ ob,
                      const float* __restrict__ hnew,
                      const float* __restrict__ ctx,
                      float* __restrict__ out) {
    int t  = threadIdx.x;
    int kb = t * 8;
    float c0[8], c1[8];
#pragma unroll
    for (int i = 0; i < 8; ++i) {
        int k = kb + i;
        c0[i] = (k < H) ? hnew[k]     : ctx[k - H];
        c1[i] = (k < H) ? hnew[H + k] : ctx[k];
    }
    __shared__ float lds[4][2];
    long obase = (long)blockIdx.x * 8;
    for (int r = 0; r < 8; ++r) {
        long o = obase + r;
        const float4* w4 = (const float4*)(ow + o * (2 * H) + kb);
        float4 wa = w4[0], wb = w4[1];
        float a0 = wa.x * c0[0] + wa.y * c0[1] + wa.z * c0[2] + wa.w * c0[3]
                 + wb.x * c0[4] + wb.y * c0[5] + wb.z * c0[6] + wb.w * c0[7];
        float a1 = wa.x * c1[0] + wa.y * c1[1] + wa.z * c1[2] + wa.w * c1[3]
                 + wb.x * c1[4] + wb.y * c1[5] + wb.z * c1[6] + wb.w * c1[7];
        for (int off = 32; off; off >>= 1) {
            a0 += __shfl_down(a0, off, 64);
            a1 += __shfl_down(a1, off, 64);
        }
        int wave = t >> 6, lane = t & 63;
        if (lane == 0) { lds[wave][0] = a0; lds[wave][1] = a1; }
        __syncthreads();
        if (t == 0) {
            float s0 = lds[0][0] + lds[1][0] + lds[2][0] + lds[3][0];
            float s1 = lds[0][1] + lds[1][1] + lds[2][1] + lds[3][1];
            float bb = ob[o];
            out[o]     = s0 + bb;
            out[V + o] = s1 + bb;
        }
        __syncthreads();
    }
}

extern "C" void kernel_launch(void* const* d_in, const int* in_sizes, int n_in,
                              void* d_out, int out_size, void* d_ws, size_t ws_size,
                              hipStream_t stream) {
    const int*   ids    = (const int*)  d_in[0];
    const float* lctx   = (const float*)d_in[1];
    const float* lhid   = (const float*)d_in[2];
    const float* enc    = (const float*)d_in[3];
    const float* emb    = (const float*)d_in[4];
    const float* w_ih   = (const float*)d_in[5];
    const float* w_hh   = (const float*)d_in[6];
    const float* b_ih   = (const float*)d_in[7];
    const float* b_hh   = (const float*)d_in[8];
    const float* attn_w = (const float*)d_in[9];
    // d_in[10] = attn_b  (unused: shift-invariant under softmax)
    const float* v      = (const float*)d_in[11];
    const float* out_w  = (const float*)d_in[12];
    const float* out_b  = (const float*)d_in[13];

    float* out_f       = (float*)d_out;
    float* o_output    = out_f;             // (2,1,50000) = 100000
    float* o_context   = out_f + 100000;    // (2,1,1024)  = 2048
    float* o_hidden    = out_f + 102048;    // (1,2,1024)  = 2048
    float* o_embedded  = out_f + 104096;    // (2,1,1024)  = 2048
    float* o_rnn       = out_f + 106144;    // (2,1,1024)  = 2048

    float* ws    = (float*)d_ws;
    float* U     = ws;                 // 1024
    float* UPART = ws + 1024;          // 16*1024
    float* EN    = ws + 17408;         // 2*8192 = 16384
    float* PART  = ws + 33792;         // 256*1024 = 262144  (~1.2 MB total)

    k_upart   <<<dim3(4, 16), 256, 0, stream>>>(attn_w, v, UPART);
    k_ured_emb<<<4,            256, 0, stream>>>(UPART, U, ids, emb, o_embedded);
    k_gru     <<<1024,         256, 0, stream>>>(ids, emb, lctx, lhid, w_ih, w_hh,
                                                 b_ih, b_hh, o_hidden, o_rnn);
    k_energy  <<<4096,         256, 0, stream>>>(enc, U, EN);
    k_softmax <<<2,           1024, 0, stream>>>(EN);
    k_ctx_part<<<256,          256, 0, stream>>>(enc, EN, PART);
    k_ctx_red <<<8,            256, 0, stream>>>(PART, o_context);
    k_out     <<<6250,         256, 0, stream>>>(out_w, out_b, o_hidden, o_context,
                                                 o_output);
}

// Round 2
// 131.642 us; speedup vs baseline: 1.0162x; 1.0162x over previous
//
#include <hip/hip_runtime.h>

#define H 1024
#define B2 2
#define LEN 8192
#define V 50000

__device__ __forceinline__ float dot4(float4 a, float4 b) {
    return a.x * b.x + a.y * b.y + a.z * b.z + a.w * b.w;
}

// ---------------------------------------------------------------------------
// K1: u partials (blocks 0..63) + embedding gather (blocks 64..71).
// u[h] = sum_k v[k] * attn_w[k*2048 + 1024 + h]
// ---------------------------------------------------------------------------
__global__ void k_upart_emb(const float* __restrict__ attn_w,
                            const float* __restrict__ v,
                            float* __restrict__ upart,
                            const int* __restrict__ ids,
                            const float* __restrict__ emb,
                            float* __restrict__ out_emb) {
    int bid = blockIdx.x;
    int t   = threadIdx.x;
    if (bid < 64) {
        int h  = (bid & 3) * 256 + t;      // 0..1023
        int kc = bid >> 2;                 // 0..15
        float acc = 0.f;
#pragma unroll 8
        for (int i = 0; i < 64; ++i) {
            int k = kc * 64 + i;
            acc += v[k] * attn_w[(long)k * (2 * H) + H + h];
        }
        upart[kc * H + h] = acc;
    } else {
        int idx = (bid - 64) * 256 + t;    // 0..2047
        int b = idx >> 10, h = idx & 1023;
        out_emb[idx] = emb[(long)ids[b] * H + h];
    }
}

// K2: reduce u partials. grid 4 x 256.
__global__ void k_ured(const float* __restrict__ upart,
                       float* __restrict__ u) {
    int h = blockIdx.x * 256 + threadIdx.x;
    float acc = 0.f;
#pragma unroll
    for (int kc = 0; kc < 16; ++kc) acc += upart[kc * H + h];
    u[h] = acc;
}

// ---------------------------------------------------------------------------
// K3: GRU cell (blocks 0..1023) + energies (blocks 1024..5119).
// GRU: one block per output element hh (6 dot-products, shfl+LDS reduce).
// Energy: wave per row, energies[row] = enc[row,:] . u
// ---------------------------------------------------------------------------
__global__ void k_gru_energy(const int* __restrict__ ids,
                             const float* __restrict__ emb,
                             const float* __restrict__ lctx,
                             const float* __restrict__ lhid,
                             const float* __restrict__ w_ih,
                             const float* __restrict__ w_hh,
                             const float* __restrict__ b_ih,
                             const float* __restrict__ b_hh,
                             const float* __restrict__ enc,
                             const float* __restrict__ u,
                             float* __restrict__ o_hidden,
                             float* __restrict__ o_rnn,
                             float* __restrict__ en) {
    __shared__ float lds[3][4][4];
    int t = threadIdx.x;

    if (blockIdx.x >= 1024) {
        // ---- energies ----
        int row  = ((blockIdx.x - 1024) << 2) + (t >> 6);   // 0..16383
        int lane = t & 63;
        const float* e = enc + (long)row * H;
        float acc = 0.f;
#pragma unroll
        for (int c = 0; c < 4; ++c) {
            int k = c * 256 + lane * 4;
            float4 ev = *(const float4*)(e + k);
            float4 uv = *(const float4*)(u + k);
            acc += dot4(ev, uv);
        }
        for (int off = 32; off; off >>= 1) acc += __shfl_down(acc, off, 64);
        if (lane == 0) en[row] = acc;
        return;
    }

    // ---- GRU ----
    int hh = blockIdx.x;          // 0..1023
    int kb = t * 8;               // x index base (0..2040)

    float4 x0a, x0b, x1a, x1b;
    if (kb < H) {
        const float* p0 = emb + (long)ids[0] * H + kb;
        const float* p1 = emb + (long)ids[1] * H + kb;
        x0a = *(const float4*)p0;       x0b = *(const float4*)(p0 + 4);
        x1a = *(const float4*)p1;       x1b = *(const float4*)(p1 + 4);
    } else {
        const float* p0 = lctx + (kb - H);
        const float* p1 = lctx + H + (kb - H);
        x0a = *(const float4*)p0;       x0b = *(const float4*)(p0 + 4);
        x1a = *(const float4*)p1;       x1b = *(const float4*)(p1 + 4);
    }
    int kb2 = t * 4;              // h index base (0..1020)
    float4 h0 = *(const float4*)(lhid + kb2);
    float4 h1 = *(const float4*)(lhid + H + kb2);

    for (int g = 0; g < 3; ++g) {
        const float* wi = w_ih + ((long)g * H + hh) * (2 * H) + kb;
        const float* wh = w_hh + ((long)g * H + hh) * H + kb2;
        float4 wa = *(const float4*)wi;
        float4 wb = *(const float4*)(wi + 4);
        float4 wc = *(const float4*)wh;
        float a0 = dot4(wa, x0a) + dot4(wb, x0b);
        float a1 = dot4(wa, x1a) + dot4(wb, x1b);
        float c0 = dot4(wc, h0);
        float c1 = dot4(wc, h1);
        for (int off = 32; off; off >>= 1) {
            a0 += __shfl_down(a0, off, 64);
            a1 += __shfl_down(a1, off, 64);
            c0 += __shfl_down(c0, off, 64);
            c1 += __shfl_down(c1, off, 64);
        }
        if ((t & 63) == 0) {
            int w = t >> 6;
            lds[g][w][0] = a0; lds[g][w][1] = a1;
            lds[g][w][2] = c0; lds[g][w][3] = c1;
        }
    }
    __syncthreads();
    if (t == 0) {
        float gx[3][2], gh[3][2];
        for (int g = 0; g < 3; ++g) {
            float s0 = 0, s1 = 0, s2 = 0, s3 = 0;
            for (int w = 0; w < 4; ++w) {
                s0 += lds[g][w][0]; s1 += lds[g][w][1];
                s2 += lds[g][w][2]; s3 += lds[g][w][3];
            }
            float bi = b_ih[g * H + hh], bh = b_hh[g * H + hh];
            gx[g][0] = s0 + bi; gx[g][1] = s1 + bi;
            gh[g][0] = s2 + bh; gh[g][1] = s3 + bh;
        }
        for (int b = 0; b < B2; ++b) {
            float r  = 1.f / (1.f + expf(-(gx[0][b] + gh[0][b])));
            float z  = 1.f / (1.f + expf(-(gx[1][b] + gh[1][b])));
            float n  = tanhf(gx[2][b] + r * gh[2][b]);
            float hp = lhid[b * H + hh];
            float hn = (1.f - z) * n + z * hp;
            o_hidden[b * H + hh] = hn;
            o_rnn[b * H + hh]    = hn;
        }
    }
}

// ---------------------------------------------------------------------------
// K4: context partials with INLINE softmax (no separate softmax kernel).
// block = (b, l-chunk of 64). Each block recomputes max/sum over the raw
// energy row (32 KB, L2-hot), builds its 64 weights in LDS, then accumulates.
// grid 256 x 256
// ---------------------------------------------------------------------------
__global__ void k_ctx(const float* __restrict__ enc,
                      const float* __restrict__ en,
                      float* __restrict__ part) {
    int b  = blockIdx.x >> 7;      // 0..1
    int lc = blockIdx.x & 127;     // 0..127
    int t  = threadIdx.x;
    const float* e_row = en + b * LEN;

    __shared__ float red[4];
    __shared__ float wlds[64];

    // block max
    float m = -3.4e38f;
    for (int i = t; i < LEN; i += 256) m = fmaxf(m, e_row[i]);
    for (int off = 32; off; off >>= 1) m = fmaxf(m, __shfl_xor(m, off, 64));
    if ((t & 63) == 0) red[t >> 6] = m;
    __syncthreads();
    m = fmaxf(fmaxf(red[0], red[1]), fmaxf(red[2], red[3]));

    // block sum of exp
    float s = 0.f;
    for (int i = t; i < LEN; i += 256) s += expf(e_row[i] - m);
    for (int off = 32; off; off >>= 1) s += __shfl_xor(s, off, 64);
    __syncthreads();                       // red reads above done
    if ((t & 63) == 0) red[t >> 6] = s;
    __syncthreads();
    float inv = 1.f / (red[0] + red[1] + red[2] + red[3]);

    if (t < 64) wlds[t] = expf(e_row[lc * 64 + t] - m) * inv;
    __syncthreads();

    const float* e = enc + ((long)b * LEN + lc * 64) * H + t * 4;
    float4 acc = {0.f, 0.f, 0.f, 0.f};
#pragma unroll 4
    for (int i = 0; i < 64; ++i) {
        float w = wlds[i];
        float4 ev = *(const float4*)(e + (long)i * H);
        acc.x += w * ev.x; acc.y += w * ev.y; acc.z += w * ev.z; acc.w += w * ev.w;
    }
    *(float4*)(part + (long)blockIdx.x * H + t * 4) = acc;
}

// K5: reduce context partials -> context output. grid 8 x 256.
__global__ void k_ctx_red(const float* __restrict__ part,
                          float* __restrict__ out_ctx) {
    int idx = blockIdx.x * 256 + threadIdx.x;  // 0..2047 = b*H+h
    int b = idx >> 10, h = idx & 1023;
    float acc = 0.f;
#pragma unroll 8
    for (int lc = 0; lc < 128; ++lc) acc += part[((b << 7) + lc) * H + h];
    out_ctx[idx] = acc;
}

// ---------------------------------------------------------------------------
// K6: output projection — wave per row, no barriers, no LDS.
// cat vector (2048 floats per batch) lives in registers, 16B/lane slices.
// grid 12500 x 256 (4 waves = 4 rows per block)
// ---------------------------------------------------------------------------
__global__ void k_out(const float* __restrict__ ow,
                      const float* __restrict__ ob,
                      const float* __restrict__ hnew,
                      const float* __restrict__ ctx,
                      float* __restrict__ out) {
    int t    = threadIdx.x;
    int lane = t & 63;
    int wv   = t >> 6;
    long row = (long)blockIdx.x * 4 + wv;      // 0..49999

    float4 c0[8], c1[8];
#pragma unroll
    for (int j = 0; j < 4; ++j) {              // k = (lane+64j)*4 < 1024
        int k = (lane + 64 * j) * 4;
        c0[j] = *(const float4*)(hnew + k);
        c1[j] = *(const float4*)(hnew + H + k);
    }
#pragma unroll
    for (int j = 4; j < 8; ++j) {              // k >= 1024 -> context part
        int k = (lane + 64 * j) * 4 - H;
        c0[j] = *(const float4*)(ctx + k);
        c1[j] = *(const float4*)(ctx + H + k);
    }

    const float4* w4 = (const float4*)(ow + row * (2 * H));
    float a0 = 0.f, a1 = 0.f;
#pragma unroll
    for (int j = 0; j < 8; ++j) {
        float4 w = w4[lane + 64 * j];
        a0 += dot4(w, c0[j]);
        a1 += dot4(w, c1[j]);
    }
    for (int off = 32; off; off >>= 1) {
        a0 += __shfl_down(a0, off, 64);
        a1 += __shfl_down(a1, off, 64);
    }
    if (lane == 0) {
        float bb = ob[row];
        out[row]     = a0 + bb;
        out[V + row] = a1 + bb;
    }
}

extern "C" void kernel_launch(void* const* d_in, const int* in_sizes, int n_in,
                              void* d_out, int out_size, void* d_ws, size_t ws_size,
                              hipStream_t stream) {
    const int*   ids    = (const int*)  d_in[0];
    const float* lctx   = (const float*)d_in[1];
    const float* lhid   = (const float*)d_in[2];
    const float* enc    = (const float*)d_in[3];
    const float* emb    = (const float*)d_in[4];
    const float* w_ih   = (const float*)d_in[5];
    const float* w_hh   = (const float*)d_in[6];
    const float* b_ih   = (const float*)d_in[7];
    const float* b_hh   = (const float*)d_in[8];
    const float* attn_w = (const float*)d_in[9];
    // d_in[10] = attn_b  (unused: shift-invariant under softmax)
    const float* v      = (const float*)d_in[11];
    const float* out_w  = (const float*)d_in[12];
    const float* out_b  = (const float*)d_in[13];

    float* out_f       = (float*)d_out;
    float* o_output    = out_f;             // (2,1,50000) = 100000
    float* o_context   = out_f + 100000;    // (2,1,1024)  = 2048
    float* o_hidden    = out_f + 102048;    // (1,2,1024)  = 2048
    float* o_embedded  = out_f + 104096;    // (2,1,1024)  = 2048
    float* o_rnn       = out_f + 106144;    // (2,1,1024)  = 2048

    float* ws    = (float*)d_ws;
    float* U     = ws;                 // 1024
    float* UPART = ws + 1024;          // 16*1024
    float* EN    = ws + 17408;         // 2*8192 = 16384
    float* PART  = ws + 33792;         // 256*1024 = 262144

    k_upart_emb <<<72,    256, 0, stream>>>(attn_w, v, UPART, ids, emb, o_embedded);
    k_ured      <<<4,     256, 0, stream>>>(UPART, U);
    k_gru_energy<<<5120,  256, 0, stream>>>(ids, emb, lctx, lhid, w_ih, w_hh,
                                            b_ih, b_hh, enc, U,
                                            o_hidden, o_rnn, EN);
    k_ctx       <<<256,   256, 0, stream>>>(enc, EN, PART);
    k_ctx_red   <<<8,     256, 0, stream>>>(PART, o_context);
    k_out       <<<12500, 256, 0, stream>>>(out_w, out_b, o_hidden, o_context,
                                            o_output);
}